// Round 18
// baseline (238.689 us; speedup 1.0000x reference)
//
#include <hip/hip_runtime.h>
#include <hip/hip_bf16.h>
#include <hip/hip_fp16.h>
#include <math.h>

#define B 2
#define N 1024
#define D 128
#define DA 32
#define NH 4
#define AH 32
#define DEC_H 256
#define DEC_O 128
#define C_DIM ((NH + 1) * D)   // 640
#define TI 32
#define TJ 32
#define SPLIT 4                // j-dimension split
#define JCHUNK (N / SPLIT)     // 256 -> 8 j-tiles per block

typedef __attribute__((ext_vector_type(8))) short bf16x8;
typedef __attribute__((ext_vector_type(4))) float f32x4;

// round-to-nearest-even f32 -> bf16
static __device__ __forceinline__ unsigned pack2bf(float a, float b) {
    unsigned ua = __float_as_uint(a), ub = __float_as_uint(b);
    unsigned ra = (ua + 0x7FFFu + ((ua >> 16) & 1u)) >> 16;
    unsigned rb = (ub + 0x7FFFu + ((ub >> 16) & 1u)) >> 16;
    return (ra & 0xFFFFu) | (rb << 16);
}
static __device__ __forceinline__ unsigned short tobf(float a) {
    unsigned ua = __float_as_uint(a);
    return (unsigned short)((ua + 0x7FFFu + ((ua >> 16) & 1u)) >> 16);
}
// sigmoid(0.5*s) = rcp(1 + 2^(-0.5*log2e*s)); saturates to 0 for masked s
static __device__ __forceinline__ float fast_sig_half(float s) {
    return __builtin_amdgcn_rcpf(1.f + __builtin_amdgcn_exp2f(-0.72134752f * s));
}
static __device__ __forceinline__ __half2 bc_h2(unsigned u) {
    return __builtin_bit_cast(__half2, u);
}

// A-tiled bf16 index for [rows][cols] tiled [mm][kk][16][32]
static __device__ __forceinline__ int atile_idx(int row, int col, int KT) {
    return ((row >> 4) * KT + (col >> 5)) * 512 + (row & 15) * 32 + (col & 31);
}

// ---------------- kernel 1: fused qkv + hk/hq(f16-packed) + pk2/pq2 + weight tiling ----------------
__global__ __launch_bounds__(384) void qkvh_kernel(
    const float* __restrict__ x,
    const float* __restrict__ Wk, const float* __restrict__ bk,
    const float* __restrict__ Wq, const float* __restrict__ bq,
    const float* __restrict__ Wv, const float* __restrict__ bv,
    const float* __restrict__ Wa1, const float* __restrict__ ba1,
    const float* __restrict__ Wa2, const float* __restrict__ ba2,
    const float* __restrict__ Wd1, const float* __restrict__ Wd2,
    unsigned short* __restrict__ vT8, unsigned short* __restrict__ cbfT,
    unsigned* __restrict__ hkP, unsigned* __restrict__ hqP,
    float* __restrict__ pkOut, float* __restrict__ pqOut,
    unsigned short* __restrict__ wd1t, unsigned short* __restrict__ wd2t,
    unsigned* __restrict__ wa2P)
{
    const int t = threadIdx.x;
    if (blockIdx.x >= 512) {   // weight pre-tiling branch
        const int bid = blockIdx.x - 512;
        if (bid < 640) {
            if (bid == 0 && t >= 256 && t < 272)   // pack Wa2 -> f16x2 (16 u32)
                wa2P[t - 256] = __builtin_bit_cast(unsigned,
                    __floats2half2_rn(Wa2[2 * (t - 256)], Wa2[2 * (t - 256) + 1]));
            if (t < 256) wd1t[(bid >> 5) * 8192 + t * 32 + (bid & 31)] = tobf(Wd1[(size_t)bid * 256 + t]);
        } else {
            const int d = bid - 640;
            if (t < 128) wd2t[(d >> 5) * 4096 + t * 32 + (d & 31)] = tobf(Wd2[(size_t)d * 128 + t]);
        }
        return;
    }

    const int row0 = blockIdx.x * 4;
    __shared__ float xs[4][D];
    __shared__ float kq[2][4][D];
    __shared__ float hls[2][4][NH][DA];

    for (int idx = t; idx < 4 * D; idx += 384)
        xs[idx >> 7][idx & 127] = x[(size_t)row0 * D + idx];
    __syncthreads();

    {   // projections
        const int mat = t >> 7;      // 0=k,1=q,2=v (wave-uniform)
        const int col = t & 127;
        const float* W = (mat == 0) ? Wk : (mat == 1) ? Wq : Wv;
        const float bias = (mat == 0) ? bk[col] : (mat == 1) ? bq[col] : bv[col];
        float a[4];
        #pragma unroll
        for (int m = 0; m < 4; ++m) a[m] = bias;
        for (int d = 0; d < D; ++d) {
            const float w = W[d * D + col];
            #pragma unroll
            for (int m = 0; m < 4; ++m) a[m] = fmaf(xs[m][d], w, a[m]);
        }
        if (mat < 2) {
            #pragma unroll
            for (int m = 0; m < 4; ++m) kq[mat][m][col] = a[m];
        } else {
            #pragma unroll
            for (int m = 0; m < 4; ++m)
                cbfT[atile_idx(row0 + m, col, 20)] = tobf(a[m]);
            const int b = row0 >> 10, n = row0 & (N - 1);
            uint2 pk2;
            pk2.x = pack2bf(a[0], a[1]);
            pk2.y = pack2bf(a[2], a[3]);
            unsigned short* dst = vT8 + (((size_t)b * (N >> 3) + (n >> 3)) * D + col) * 8 + (n & 7);
            *reinterpret_cast<uint2*>(dst) = pk2;
        }
    }
    __syncthreads();

    // hk/hq: 1024 values into LDS
    for (int e = t; e < 1024; e += 384) {
        const int isq = e >> 9;
        const int rh = (e >> 7) & 3;
        const int hd = (e >> 5) & 3;
        const int a = e & 31;
        const float* src = &kq[isq][rh][hd * DA];
        const float* W = Wa1 + isq * DA * AH;
        float acc = isq ? ba1[a] : 0.f;
        #pragma unroll
        for (int c = 0; c < DA; ++c)
            acc = fmaf(src[c], W[c * AH + a], acc);
        hls[isq][rh][hd][a] = acc;
    }
    __syncthreads();

    // packed f16 hk/hq global write (512 u32)
    for (int e = t; e < 512; e += 384) {
        const int isq = e >> 8;
        const int rh = (e >> 6) & 3;
        const int hd = (e >> 4) & 3;
        const int a2 = e & 15;
        const __half2 h = __floats2half2_rn(hls[isq][rh][hd][2 * a2], hls[isq][rh][hd][2 * a2 + 1]);
        const int grow = row0 + rh;
        const int b = grow >> 10, n = grow & (N - 1);
        unsigned* dst = (isq ? hqP : hkP) + (((size_t)(b * NH + hd)) * N + n) * 16 + a2;
        *dst = __builtin_bit_cast(unsigned, h);
    }

    // linear score terms: pk2 = sum_a Wa2*hk + 2*ba2 ; pq2 = sum_a Wa2*hq
    if (t < 32) {
        const int isq = t >> 4;
        const int rh = (t >> 2) & 3;
        const int hd = t & 3;
        float p = isq ? 0.f : 2.f * ba2[0];
        #pragma unroll
        for (int a = 0; a < 32; ++a)
            p = fmaf(Wa2[a], hls[isq][rh][hd][a], p);
        const int grow = row0 + rh;
        const int b = grow >> 10, n = grow & (N - 1);
        float* dst = isq ? pqOut : pkOut;
        dst[(size_t)(b * NH + hd) * N + n] = p;
    }
}

// ---------------- kernel 2: attention + last-block split-k reduce ----------------
// grid = 1024 blocks x 256 threads = exactly 4 blocks/CU (do not change).
// After writing its bf16 partial, each block release-fences and bumps a
// per-(bh,tile) counter; the 4th arriver acquire-fences and performs the
// reduce (same arithmetic/order/coalescing as the old reduce_kernel) into
// cbfT. Deterministic: fixed sc-order summation; only WHICH block reduces
// varies. Saves a launch + a dependency gap.
__global__ __launch_bounds__(256, 4) void attn_kernel(
    const unsigned* __restrict__ hkP, const unsigned* __restrict__ hqP,
    const unsigned* __restrict__ wa2P,
    const float* __restrict__ pk, const float* __restrict__ pq,
    const unsigned short* __restrict__ vT8, unsigned short* __restrict__ pBufH,
    unsigned short* __restrict__ cbfT, unsigned* __restrict__ cnt)
{
    const int t = threadIdx.x;
    const int sc = blockIdx.x & (SPLIT - 1);
    const int tile = (blockIdx.x >> 2) & 31;
    const int bh = blockIdx.x >> 7;     // b*NH + h
    const int b = bh >> 2;
    const int i0 = tile * TI;

    __shared__ unsigned hqs[2][TJ][20];    // f16x2, 80B rows
    __shared__ unsigned wbf[2][TI][20];    // bf16 w[i][j], 80B rows
    __shared__ unsigned lastFlag;

    const int ti2 = (t >> 4) << 1;
    const int tjA = t & 15;
    const float pkA = pk[(size_t)bh * N + i0 + ti2];
    const float pkB = pk[(size_t)bh * N + i0 + ti2 + 1];

    // k row-pair in NAMED registers (f16 packed; 8 uint4 = 32 VGPR)
    const uint4* kr0 = reinterpret_cast<const uint4*>(hkP + ((size_t)bh * N + i0 + ti2) * 16);
    const uint4* kr1 = reinterpret_cast<const uint4*>(hkP + ((size_t)bh * N + i0 + ti2 + 1) * 16);
    const uint4 kA0 = kr0[0], kA1 = kr0[1], kA2 = kr0[2], kA3 = kr0[3];
    const uint4 kB0 = kr1[0], kB1 = kr1[1], kB2 = kr1[2], kB3 = kr1[3];

    const int lane = t & 63;
    const int wv = t >> 6;
    const int lm = lane & 15;
    const int lg = lane >> 4;
    const int d0 = (2 * wv) * 16 + lm;
    const int d1 = d0 + 16;

    f32x4 acc00 = {0.f, 0.f, 0.f, 0.f};
    f32x4 acc01 = {0.f, 0.f, 0.f, 0.f};
    f32x4 acc10 = {0.f, 0.f, 0.f, 0.f};
    f32x4 acc11 = {0.f, 0.f, 0.f, 0.f};

    const int jbeg = sc * JCHUNK;
    {   // prologue: stage hqs[0] (512 u32)
        const unsigned* srcq = hqP + ((size_t)bh * N + jbeg) * 16;
        for (int idx = t; idx < 512; idx += 256)
            hqs[0][idx >> 4][idx & 15] = srcq[idx];
    }
    __syncthreads();

    #pragma unroll 2
    for (int it = 0; it < JCHUNK / TJ; ++it) {
        const int j0 = jbeg + it * TJ;
        const int cur = it & 1;

        const unsigned short* vb = vT8 + (((size_t)b * (N >> 3) + (j0 >> 3) + lg) * D) * 8;
        const bf16x8 b0 = *reinterpret_cast<const bf16x8*>(vb + d0 * 8);
        const bf16x8 b1 = *reinterpret_cast<const bf16x8*>(vb + d1 * 8);
        const float pqA = pq[(size_t)bh * N + j0 + tjA];
        const float pqB = pq[(size_t)bh * N + j0 + tjA + 16];

        {   // scores: packed-f16; k from regs, q from LDS, w from SGPRs
            __half2 sAA2 = bc_h2(0u), sAB2 = bc_h2(0u), sBA2 = bc_h2(0u), sBB2 = bc_h2(0u);
#define SSTEP(ku, ku2, qu, qu2, wi)                                                     \
            {                                                                           \
                const __half2 kAh = bc_h2(ku), kBh = bc_h2(ku2);                        \
                const __half2 qAh = bc_h2(qu), qBh = bc_h2(qu2);                        \
                const __half2 wwh = bc_h2(wa2P[wi]);                                    \
                sAA2 = __hfma2(wwh, __habs2(__hadd2(kAh, qAh)), sAA2);                  \
                sAB2 = __hfma2(wwh, __habs2(__hadd2(kAh, qBh)), sAB2);                  \
                sBA2 = __hfma2(wwh, __habs2(__hadd2(kBh, qAh)), sBA2);                  \
                sBB2 = __hfma2(wwh, __habs2(__hadd2(kBh, qBh)), sBB2);                  \
            }
#define SGROUP(kAu, kBu, s8)                                                            \
            {                                                                           \
                const uint4 qAu = *reinterpret_cast<const uint4*>(&hqs[cur][tjA][(s8) * 4]);      \
                const uint4 qBu = *reinterpret_cast<const uint4*>(&hqs[cur][tjA + 16][(s8) * 4]); \
                SSTEP(kAu.x, kBu.x, qAu.x, qBu.x, (s8) * 4 + 0)                         \
                SSTEP(kAu.y, kBu.y, qAu.y, qBu.y, (s8) * 4 + 1)                         \
                SSTEP(kAu.z, kBu.z, qAu.z, qBu.z, (s8) * 4 + 2)                         \
                SSTEP(kAu.w, kBu.w, qAu.w, qBu.w, (s8) * 4 + 3)                         \
            }
            SGROUP(kA0, kB0, 0) SGROUP(kA1, kB1, 1) SGROUP(kA2, kB2, 2) SGROUP(kA3, kB3, 3)
#undef SSTEP
#undef SGROUP
            const float2 fAA = __half22float2(sAA2);
            const float2 fAB = __half22float2(sAB2);
            const float2 fBA = __half22float2(sBA2);
            const float2 fBB = __half22float2(sBB2);
            float sAA = pkA + pqA + fAA.x + fAA.y;
            float sAB = pkA + pqB + fAB.x + fAB.y;
            float sBA = pkB + pqA + fBA.x + fBA.y;
            float sBB = pkB + pqB + fBB.x + fBB.y;
            const int giA = i0 + ti2, giB = giA + 1;
            const int gjA = j0 + tjA, gjB = gjA + 16;
            if (giA == gjA) sAA -= 20000.f;
            if (giA == gjB) sAB -= 20000.f;
            if (giB == gjA) sBA -= 20000.f;
            if (giB == gjB) sBB -= 20000.f;
            unsigned short* wb = reinterpret_cast<unsigned short*>(&wbf[cur][0][0]);
            wb[ti2 * 40 + tjA]            = tobf(fast_sig_half(sAA));
            wb[ti2 * 40 + tjA + 16]       = tobf(fast_sig_half(sAB));
            wb[(ti2 + 1) * 40 + tjA]      = tobf(fast_sig_half(sBA));
            wb[(ti2 + 1) * 40 + tjA + 16] = tobf(fast_sig_half(sBB));
        }

        // stage next iter's hq
        if (it + 1 < JCHUNK / TJ) {
            const unsigned* srcq = hqP + ((size_t)bh * N + j0 + TJ) * 16;
            for (int idx = t; idx < 512; idx += 256)
                hqs[cur ^ 1][idx >> 4][idx & 15] = srcq[idx];
        }

        __syncthreads();   // wbf[cur] ready; hqs[cur^1] staged

        {   // PV: 4x mfma per wave
            const char* wbase = reinterpret_cast<const char*>(&wbf[cur][0][0]);
            const bf16x8 a0 = *reinterpret_cast<const bf16x8*>(wbase + lm * 80 + lg * 16);
            const bf16x8 a1 = *reinterpret_cast<const bf16x8*>(wbase + (16 + lm) * 80 + lg * 16);
            acc00 = __builtin_amdgcn_mfma_f32_16x16x32_bf16(a0, b0, acc00, 0, 0, 0);
            acc01 = __builtin_amdgcn_mfma_f32_16x16x32_bf16(a0, b1, acc01, 0, 0, 0);
            acc10 = __builtin_amdgcn_mfma_f32_16x16x32_bf16(a1, b0, acc10, 0, 0, 0);
            acc11 = __builtin_amdgcn_mfma_f32_16x16x32_bf16(a1, b1, acc11, 0, 0, 0);
        }
    }

    // write 32x128 partial tile (bf16) to pBufH[blockIdx.x]
    unsigned short* dst = pBufH + (size_t)blockIdx.x * (TI * D);
    #pragma unroll
    for (int r = 0; r < 4; ++r) {
        const int ia = lg * 4 + r;
        dst[ia * D + d0]        = tobf(acc00[r]);
        dst[ia * D + d1]        = tobf(acc01[r]);
        dst[(16 + ia) * D + d0] = tobf(acc10[r]);
        dst[(16 + ia) * D + d1] = tobf(acc11[r]);
    }

    // ---- split-k epilogue: last arriver reduces this (bh,tile) ----
    __threadfence();   // release: make partial visible device-wide
    if (t == 0) {
        const unsigned old = atomicAdd(&cnt[bh * 32 + tile], 1u);
        lastFlag = (old == SPLIT - 1) ? 1u : 0u;
    }
    __syncthreads();
    if (lastFlag) {
        __threadfence();   // acquire: invalidate before reading others' partials
        const uint4* p = reinterpret_cast<const uint4*>(pBufH)
                       + (size_t)(bh * 32 + tile) * SPLIT * 512;
        const int h = bh & 3;
        #pragma unroll
        for (int u8 = t; u8 < 512; u8 += 256) {
            const int dg = u8 & 15;        // 8-col group
            const int i  = u8 >> 4;        // row 0..31
            float s0 = 0.f, s1 = 0.f, s2 = 0.f, s3 = 0.f, s4 = 0.f, s5 = 0.f, s6 = 0.f, s7 = 0.f;
            #pragma unroll
            for (int sc2 = 0; sc2 < SPLIT; ++sc2) {
                const uint4 u = p[sc2 * 512 + i * 16 + dg];
                s0 += __uint_as_float(u.x << 16); s1 += __uint_as_float(u.x & 0xFFFF0000u);
                s2 += __uint_as_float(u.y << 16); s3 += __uint_as_float(u.y & 0xFFFF0000u);
                s4 += __uint_as_float(u.z << 16); s5 += __uint_as_float(u.z & 0xFFFF0000u);
                s6 += __uint_as_float(u.w << 16); s7 += __uint_as_float(u.w & 0xFFFF0000u);
            }
            const int grow = b * N + tile * 32 + i;
            const int col0 = (h + 1) * 128 + dg * 8;
            uint4 o;
            o.x = pack2bf(s0, s1); o.y = pack2bf(s2, s3);
            o.z = pack2bf(s4, s5); o.w = pack2bf(s6, s7);
            *reinterpret_cast<uint4*>(&cbfT[atile_idx(grow, col0, 20)]) = o;
        }
    }
}

// ---------------- kernel 3: fused decoder (both layers, h in LDS) ----------------
__global__ __launch_bounds__(512) void dec_kernel(
    const unsigned short* __restrict__ cbfT, const unsigned short* __restrict__ wd1t,
    const float* __restrict__ bd1, const unsigned short* __restrict__ wd2t,
    const float* __restrict__ bd2, float* __restrict__ out)
{
    const int t = threadIdx.x;
    const int lane = t & 63, lm = lane & 15, lg = lane >> 4;
    const int w = t >> 6;           // wave 0..7
    const int mm = blockIdx.x;      // 0..127
    __shared__ unsigned short hbf[8 * 512];   // h A-tiled [kk][16][32], 8 KB

    const int bbase = lm * 32 + lg * 8;
    {   // dec layer 1
        f32x4 acc0 = {0.f, 0.f, 0.f, 0.f}, acc1 = {0.f, 0.f, 0.f, 0.f};
        const int abase = mm * 20 * 512 + bbase;
        #pragma unroll 4
        for (int kk = 0; kk < 20; ++kk) {
            const bf16x8 a  = *reinterpret_cast<const bf16x8*>(cbfT + abase + kk * 512);
            const bf16x8 b0 = *reinterpret_cast<const bf16x8*>(wd1t + kk * 8192 + (2 * w) * 512 + bbase);
            const bf16x8 b1 = *reinterpret_cast<const bf16x8*>(wd1t + kk * 8192 + (2 * w + 1) * 512 + bbase);
            acc0 = __builtin_amdgcn_mfma_f32_16x16x32_bf16(a, b0, acc0, 0, 0, 0);
            acc1 = __builtin_amdgcn_mfma_f32_16x16x32_bf16(a, b1, acc1, 0, 0, 0);
        }
        const float bias0 = bd1[w * 32 + lm];
        const float bias1 = bd1[w * 32 + 16 + lm];
        unsigned short* hb = hbf + w * 512;
        #pragma unroll
        for (int r = 0; r < 4; ++r) {
            const int irow = lg * 4 + r;
            hb[irow * 32 + lm]      = tobf(fmaxf(acc0[r] + bias0, 0.f));
            hb[irow * 32 + 16 + lm] = tobf(fmaxf(acc1[r] + bias1, 0.f));
        }
    }
    __syncthreads();

    if (w < 4) {   // dec layer 2
        f32x4 acc0 = {0.f, 0.f, 0.f, 0.f}, acc1 = {0.f, 0.f, 0.f, 0.f};
        #pragma unroll
        for (int kk = 0; kk < 8; ++kk) {
            const bf16x8 a  = *reinterpret_cast<const bf16x8*>(hbf + kk * 512 + bbase);
            const bf16x8 b0 = *reinterpret_cast<const bf16x8*>(wd2t + kk * 4096 + (2 * w) * 512 + bbase);
            const bf16x8 b1 = *reinterpret_cast<const bf16x8*>(wd2t + kk * 4096 + (2 * w + 1) * 512 + bbase);
            acc0 = __builtin_amdgcn_mfma_f32_16x16x32_bf16(a, b0, acc0, 0, 0, 0);
            acc1 = __builtin_amdgcn_mfma_f32_16x16x32_bf16(a, b1, acc1, 0, 0, 0);
        }
        const float bias0 = bd2[w * 32 + lm];
        const float bias1 = bd2[w * 32 + 16 + lm];
        float* op = out + (size_t)(mm * 16) * DEC_O;
        #pragma unroll
        for (int r = 0; r < 4; ++r) {
            const int irow = lg * 4 + r;
            op[irow * DEC_O + w * 32 + lm]      = acc0[r] + bias0;
            op[irow * DEC_O + w * 32 + 16 + lm] = acc1[r] + bias1;
        }
    }
}

extern "C" void kernel_launch(void* const* d_in, const int* in_sizes, int n_in,
                              void* d_out, int out_size, void* d_ws, size_t ws_size,
                              hipStream_t stream)
{
    const float* x   = (const float*)d_in[0];
    const float* Wk  = (const float*)d_in[1];
    const float* bk  = (const float*)d_in[2];
    const float* Wq  = (const float*)d_in[3];
    const float* bq  = (const float*)d_in[4];
    const float* Wv  = (const float*)d_in[5];
    const float* bv  = (const float*)d_in[6];
    const float* Wa1 = (const float*)d_in[7];
    const float* ba1 = (const float*)d_in[8];
    const float* Wa2 = (const float*)d_in[9];
    const float* ba2 = (const float*)d_in[10];
    const float* Wd1 = (const float*)d_in[11];
    const float* bd1 = (const float*)d_in[12];
    const float* Wd2 = (const float*)d_in[13];
    const float* bd2 = (const float*)d_in[14];
    float* out = (float*)d_out;

    float* ws = (float*)d_ws;
    unsigned* hkP = (unsigned*)ws;                 // 131072 u32
    unsigned* hqP = hkP + 131072;                  // 131072 u32
    float* pkBuf = (float*)(hqP + 131072);         // 8192 f32
    float* pqBuf = pkBuf + 8192;                   // 8192 f32
    unsigned short* pBufH = (unsigned short*)(pqBuf + 8192);   // 1024*4096 u16 = 8 MB
    unsigned short* cbfT = pBufH + 4194304;        // 1310720 u16
    unsigned short* wd1t = cbfT + 1310720;         // 163840 u16
    unsigned short* wd2t = wd1t + 163840;          // 32768 u16
    unsigned short* vT8  = wd2t + 32768;           // 262144 u16
    unsigned* wa2P = (unsigned*)(vT8 + 262144);    // 16 u32
    unsigned* cnt  = wa2P + 16;                    // 256 u32 split-k counters

    hipMemsetAsync(cnt, 0, 256 * sizeof(unsigned), stream);
    qkvh_kernel<<<512 + 896, 384, 0, stream>>>(x, Wk, bk, Wq, bq, Wv, bv, Wa1, ba1, Wa2, ba2,
                                               Wd1, Wd2, vT8, cbfT, hkP, hqP, pkBuf, pqBuf,
                                               wd1t, wd2t, wa2P);
    attn_kernel<<<B * NH * (N / TI) * SPLIT, 256, 0, stream>>>(hkP, hqP, wa2P, pkBuf, pqBuf, vT8,
                                                               pBufH, cbfT, cnt);
    dec_kernel<<<128, 512, 0, stream>>>(cbfT, wd1t, bd1, wd2t, bd2, out);
}

// Round 19
// 55.044 us; speedup vs baseline: 4.3364x; 4.3364x over previous
//
#include <hip/hip_runtime.h>
#include <hip/hip_bf16.h>
#include <hip/hip_fp16.h>
#include <math.h>

#define B 2
#define N 1024
#define D 128
#define DA 32
#define NH 4
#define AH 32
#define DEC_H 256
#define DEC_O 128
#define C_DIM ((NH + 1) * D)   // 640
#define TI 32
#define TJ 32
#define SPLIT 4                // j-dimension split
#define JCHUNK (N / SPLIT)     // 256 -> 8 j-tiles per block

typedef __attribute__((ext_vector_type(8))) short bf16x8;
typedef __attribute__((ext_vector_type(4))) float f32x4;

// round-to-nearest-even f32 -> bf16
static __device__ __forceinline__ unsigned pack2bf(float a, float b) {
    unsigned ua = __float_as_uint(a), ub = __float_as_uint(b);
    unsigned ra = (ua + 0x7FFFu + ((ua >> 16) & 1u)) >> 16;
    unsigned rb = (ub + 0x7FFFu + ((ub >> 16) & 1u)) >> 16;
    return (ra & 0xFFFFu) | (rb << 16);
}
static __device__ __forceinline__ unsigned short tobf(float a) {
    unsigned ua = __float_as_uint(a);
    return (unsigned short)((ua + 0x7FFFu + ((ua >> 16) & 1u)) >> 16);
}
// sigmoid(0.5*s) = rcp(1 + 2^(-0.5*log2e*s)); saturates to 0 for masked s
static __device__ __forceinline__ float fast_sig_half(float s) {
    return __builtin_amdgcn_rcpf(1.f + __builtin_amdgcn_exp2f(-0.72134752f * s));
}
static __device__ __forceinline__ __half2 bc_h2(unsigned u) {
    return __builtin_bit_cast(__half2, u);
}

// A-tiled bf16 index for [rows][cols] tiled [mm][kk][16][32]
static __device__ __forceinline__ int atile_idx(int row, int col, int KT) {
    return ((row >> 4) * KT + (col >> 5)) * 512 + (row & 15) * 32 + (col & 31);
}

// ---------------- kernel 1: fused qkv + hk/hq(f16-packed) + pk2/pq2 + weight tiling ----------------
__global__ __launch_bounds__(384) void qkvh_kernel(
    const float* __restrict__ x,
    const float* __restrict__ Wk, const float* __restrict__ bk,
    const float* __restrict__ Wq, const float* __restrict__ bq,
    const float* __restrict__ Wv, const float* __restrict__ bv,
    const float* __restrict__ Wa1, const float* __restrict__ ba1,
    const float* __restrict__ Wa2, const float* __restrict__ ba2,
    const float* __restrict__ Wd1, const float* __restrict__ Wd2,
    unsigned short* __restrict__ vT8, unsigned short* __restrict__ cbfT,
    unsigned* __restrict__ hkP, unsigned* __restrict__ hqP,
    float* __restrict__ pkOut, float* __restrict__ pqOut,
    unsigned short* __restrict__ wd1t, unsigned short* __restrict__ wd2t,
    unsigned* __restrict__ wa2P)
{
    const int t = threadIdx.x;
    if (blockIdx.x >= 512) {   // weight pre-tiling branch
        const int bid = blockIdx.x - 512;
        if (bid < 640) {
            if (bid == 0 && t >= 256 && t < 272)   // pack Wa2 -> f16x2 (16 u32)
                wa2P[t - 256] = __builtin_bit_cast(unsigned,
                    __floats2half2_rn(Wa2[2 * (t - 256)], Wa2[2 * (t - 256) + 1]));
            if (t < 256) wd1t[(bid >> 5) * 8192 + t * 32 + (bid & 31)] = tobf(Wd1[(size_t)bid * 256 + t]);
        } else {
            const int d = bid - 640;
            if (t < 128) wd2t[(d >> 5) * 4096 + t * 32 + (d & 31)] = tobf(Wd2[(size_t)d * 128 + t]);
        }
        return;
    }

    const int row0 = blockIdx.x * 4;
    __shared__ float xs[4][D];
    __shared__ float kq[2][4][D];
    __shared__ float hls[2][4][NH][DA];

    for (int idx = t; idx < 4 * D; idx += 384)
        xs[idx >> 7][idx & 127] = x[(size_t)row0 * D + idx];
    __syncthreads();

    {   // projections
        const int mat = t >> 7;      // 0=k,1=q,2=v (wave-uniform)
        const int col = t & 127;
        const float* W = (mat == 0) ? Wk : (mat == 1) ? Wq : Wv;
        const float bias = (mat == 0) ? bk[col] : (mat == 1) ? bq[col] : bv[col];
        float a[4];
        #pragma unroll
        for (int m = 0; m < 4; ++m) a[m] = bias;
        for (int d = 0; d < D; ++d) {
            const float w = W[d * D + col];
            #pragma unroll
            for (int m = 0; m < 4; ++m) a[m] = fmaf(xs[m][d], w, a[m]);
        }
        if (mat < 2) {
            #pragma unroll
            for (int m = 0; m < 4; ++m) kq[mat][m][col] = a[m];
        } else {
            #pragma unroll
            for (int m = 0; m < 4; ++m)
                cbfT[atile_idx(row0 + m, col, 20)] = tobf(a[m]);
            const int b = row0 >> 10, n = row0 & (N - 1);
            uint2 pk2;
            pk2.x = pack2bf(a[0], a[1]);
            pk2.y = pack2bf(a[2], a[3]);
            unsigned short* dst = vT8 + (((size_t)b * (N >> 3) + (n >> 3)) * D + col) * 8 + (n & 7);
            *reinterpret_cast<uint2*>(dst) = pk2;
        }
    }
    __syncthreads();

    // hk/hq: 1024 values into LDS
    for (int e = t; e < 1024; e += 384) {
        const int isq = e >> 9;
        const int rh = (e >> 7) & 3;
        const int hd = (e >> 5) & 3;
        const int a = e & 31;
        const float* src = &kq[isq][rh][hd * DA];
        const float* W = Wa1 + isq * DA * AH;
        float acc = isq ? ba1[a] : 0.f;
        #pragma unroll
        for (int c = 0; c < DA; ++c)
            acc = fmaf(src[c], W[c * AH + a], acc);
        hls[isq][rh][hd][a] = acc;
    }
    __syncthreads();

    // packed f16 hk/hq global write (512 u32)
    for (int e = t; e < 512; e += 384) {
        const int isq = e >> 8;
        const int rh = (e >> 6) & 3;
        const int hd = (e >> 4) & 3;
        const int a2 = e & 15;
        const __half2 h = __floats2half2_rn(hls[isq][rh][hd][2 * a2], hls[isq][rh][hd][2 * a2 + 1]);
        const int grow = row0 + rh;
        const int b = grow >> 10, n = grow & (N - 1);
        unsigned* dst = (isq ? hqP : hkP) + (((size_t)(b * NH + hd)) * N + n) * 16 + a2;
        *dst = __builtin_bit_cast(unsigned, h);
    }

    // linear score terms: pk2 = sum_a Wa2*hk + 2*ba2 ; pq2 = sum_a Wa2*hq
    if (t < 32) {
        const int isq = t >> 4;
        const int rh = (t >> 2) & 3;
        const int hd = t & 3;
        float p = isq ? 0.f : 2.f * ba2[0];
        #pragma unroll
        for (int a = 0; a < 32; ++a)
            p = fmaf(Wa2[a], hls[isq][rh][hd][a], p);
        const int grow = row0 + rh;
        const int b = grow >> 10, n = grow & (N - 1);
        float* dst = isq ? pqOut : pkOut;
        dst[(size_t)(b * NH + hd) * N + n] = p;
    }
}

// ---------------- kernel 2: attention (f16 k in registers, Wa2 in SGPRs) ----------------
// grid = 1024 blocks x 256 threads = exactly 4 blocks/CU (do not change).
__global__ __launch_bounds__(256, 4) void attn_kernel(
    const unsigned* __restrict__ hkP, const unsigned* __restrict__ hqP,
    const unsigned* __restrict__ wa2P,
    const float* __restrict__ pk, const float* __restrict__ pq,
    const unsigned short* __restrict__ vT8, unsigned short* __restrict__ pBufH)
{
    const int t = threadIdx.x;
    const int sc = blockIdx.x & (SPLIT - 1);
    const int tile = (blockIdx.x >> 2) & 31;
    const int bh = blockIdx.x >> 7;     // b*NH + h
    const int b = bh >> 2;
    const int i0 = tile * TI;

    __shared__ unsigned hqs[2][TJ][20];    // f16x2, 80B rows
    __shared__ unsigned wbf[2][TI][20];    // bf16 w[i][j], 80B rows

    const int ti2 = (t >> 4) << 1;
    const int tjA = t & 15;
    const float pkA = pk[(size_t)bh * N + i0 + ti2];
    const float pkB = pk[(size_t)bh * N + i0 + ti2 + 1];

    // k row-pair in NAMED registers (f16 packed; 8 uint4 = 32 VGPR)
    const uint4* kr0 = reinterpret_cast<const uint4*>(hkP + ((size_t)bh * N + i0 + ti2) * 16);
    const uint4* kr1 = reinterpret_cast<const uint4*>(hkP + ((size_t)bh * N + i0 + ti2 + 1) * 16);
    const uint4 kA0 = kr0[0], kA1 = kr0[1], kA2 = kr0[2], kA3 = kr0[3];
    const uint4 kB0 = kr1[0], kB1 = kr1[1], kB2 = kr1[2], kB3 = kr1[3];

    const int lane = t & 63;
    const int wv = t >> 6;
    const int lm = lane & 15;
    const int lg = lane >> 4;
    const int d0 = (2 * wv) * 16 + lm;
    const int d1 = d0 + 16;

    f32x4 acc00 = {0.f, 0.f, 0.f, 0.f};
    f32x4 acc01 = {0.f, 0.f, 0.f, 0.f};
    f32x4 acc10 = {0.f, 0.f, 0.f, 0.f};
    f32x4 acc11 = {0.f, 0.f, 0.f, 0.f};

    const int jbeg = sc * JCHUNK;
    {   // prologue: stage hqs[0] (512 u32)
        const unsigned* srcq = hqP + ((size_t)bh * N + jbeg) * 16;
        for (int idx = t; idx < 512; idx += 256)
            hqs[0][idx >> 4][idx & 15] = srcq[idx];
    }
    __syncthreads();

    #pragma unroll 2
    for (int it = 0; it < JCHUNK / TJ; ++it) {
        const int j0 = jbeg + it * TJ;
        const int cur = it & 1;

        const unsigned short* vb = vT8 + (((size_t)b * (N >> 3) + (j0 >> 3) + lg) * D) * 8;
        const bf16x8 b0 = *reinterpret_cast<const bf16x8*>(vb + d0 * 8);
        const bf16x8 b1 = *reinterpret_cast<const bf16x8*>(vb + d1 * 8);
        const float pqA = pq[(size_t)bh * N + j0 + tjA];
        const float pqB = pq[(size_t)bh * N + j0 + tjA + 16];

        {   // scores: packed-f16; k from regs, q from LDS, w from SGPRs
            __half2 sAA2 = bc_h2(0u), sAB2 = bc_h2(0u), sBA2 = bc_h2(0u), sBB2 = bc_h2(0u);
#define SSTEP(ku, ku2, qu, qu2, wi)                                                     \
            {                                                                           \
                const __half2 kAh = bc_h2(ku), kBh = bc_h2(ku2);                        \
                const __half2 qAh = bc_h2(qu), qBh = bc_h2(qu2);                        \
                const __half2 wwh = bc_h2(wa2P[wi]);                                    \
                sAA2 = __hfma2(wwh, __habs2(__hadd2(kAh, qAh)), sAA2);                  \
                sAB2 = __hfma2(wwh, __habs2(__hadd2(kAh, qBh)), sAB2);                  \
                sBA2 = __hfma2(wwh, __habs2(__hadd2(kBh, qAh)), sBA2);                  \
                sBB2 = __hfma2(wwh, __habs2(__hadd2(kBh, qBh)), sBB2);                  \
            }
#define SGROUP(kAu, kBu, s8)                                                            \
            {                                                                           \
                const uint4 qAu = *reinterpret_cast<const uint4*>(&hqs[cur][tjA][(s8) * 4]);      \
                const uint4 qBu = *reinterpret_cast<const uint4*>(&hqs[cur][tjA + 16][(s8) * 4]); \
                SSTEP(kAu.x, kBu.x, qAu.x, qBu.x, (s8) * 4 + 0)                         \
                SSTEP(kAu.y, kBu.y, qAu.y, qBu.y, (s8) * 4 + 1)                         \
                SSTEP(kAu.z, kBu.z, qAu.z, qBu.z, (s8) * 4 + 2)                         \
                SSTEP(kAu.w, kBu.w, qAu.w, qBu.w, (s8) * 4 + 3)                         \
            }
            SGROUP(kA0, kB0, 0) SGROUP(kA1, kB1, 1) SGROUP(kA2, kB2, 2) SGROUP(kA3, kB3, 3)
#undef SSTEP
#undef SGROUP
            const float2 fAA = __half22float2(sAA2);
            const float2 fAB = __half22float2(sAB2);
            const float2 fBA = __half22float2(sBA2);
            const float2 fBB = __half22float2(sBB2);
            float sAA = pkA + pqA + fAA.x + fAA.y;
            float sAB = pkA + pqB + fAB.x + fAB.y;
            float sBA = pkB + pqA + fBA.x + fBA.y;
            float sBB = pkB + pqB + fBB.x + fBB.y;
            const int giA = i0 + ti2, giB = giA + 1;
            const int gjA = j0 + tjA, gjB = gjA + 16;
            if (giA == gjA) sAA -= 20000.f;
            if (giA == gjB) sAB -= 20000.f;
            if (giB == gjA) sBA -= 20000.f;
            if (giB == gjB) sBB -= 20000.f;
            unsigned short* wb = reinterpret_cast<unsigned short*>(&wbf[cur][0][0]);
            wb[ti2 * 40 + tjA]            = tobf(fast_sig_half(sAA));
            wb[ti2 * 40 + tjA + 16]       = tobf(fast_sig_half(sAB));
            wb[(ti2 + 1) * 40 + tjA]      = tobf(fast_sig_half(sBA));
            wb[(ti2 + 1) * 40 + tjA + 16] = tobf(fast_sig_half(sBB));
        }

        // stage next iter's hq
        if (it + 1 < JCHUNK / TJ) {
            const unsigned* srcq = hqP + ((size_t)bh * N + j0 + TJ) * 16;
            for (int idx = t; idx < 512; idx += 256)
                hqs[cur ^ 1][idx >> 4][idx & 15] = srcq[idx];
        }

        __syncthreads();   // wbf[cur] ready; hqs[cur^1] staged

        {   // PV: 4x mfma per wave
            const char* wbase = reinterpret_cast<const char*>(&wbf[cur][0][0]);
            const bf16x8 a0 = *reinterpret_cast<const bf16x8*>(wbase + lm * 80 + lg * 16);
            const bf16x8 a1 = *reinterpret_cast<const bf16x8*>(wbase + (16 + lm) * 80 + lg * 16);
            acc00 = __builtin_amdgcn_mfma_f32_16x16x32_bf16(a0, b0, acc00, 0, 0, 0);
            acc01 = __builtin_amdgcn_mfma_f32_16x16x32_bf16(a0, b1, acc01, 0, 0, 0);
            acc10 = __builtin_amdgcn_mfma_f32_16x16x32_bf16(a1, b0, acc10, 0, 0, 0);
            acc11 = __builtin_amdgcn_mfma_f32_16x16x32_bf16(a1, b1, acc11, 0, 0, 0);
        }
    }

    // write 32x128 partial tile (bf16) to pBufH[blockIdx.x]
    unsigned short* dst = pBufH + (size_t)blockIdx.x * (TI * D);
    #pragma unroll
    for (int r = 0; r < 4; ++r) {
        const int ia = lg * 4 + r;
        dst[ia * D + d0]        = tobf(acc00[r]);
        dst[ia * D + d1]        = tobf(acc01[r]);
        dst[(16 + ia) * D + d0] = tobf(acc10[r]);
        dst[(16 + ia) * D + d1] = tobf(acc11[r]);
    }
}

// ---------------- kernel 3: reduce SPLIT bf16 partials -> cbfT (bf16 A-tiled) ----------------
__global__ __launch_bounds__(256) void reduce_kernel(
    const unsigned short* __restrict__ pBufH, unsigned short* __restrict__ cbfT)
{
    const int e8 = blockIdx.x * 256 + threadIdx.x;   // 0 .. 131071
    const int dg = e8 & 15;            // 8-d group
    const int i = (e8 >> 4) & 31;
    const int tile = (e8 >> 9) & 31;
    const int bh = e8 >> 14;
    const uint4* p = reinterpret_cast<const uint4*>(pBufH);
    const size_t base = ((size_t)(bh * 32 + tile) * SPLIT) * 512 + i * 16 + dg;
    float s[8] = {0.f, 0.f, 0.f, 0.f, 0.f, 0.f, 0.f, 0.f};
    #pragma unroll
    for (int sc = 0; sc < SPLIT; ++sc) {
        const uint4 u = p[base + (size_t)sc * 512];
        s[0] += __uint_as_float(u.x << 16); s[1] += __uint_as_float(u.x & 0xFFFF0000u);
        s[2] += __uint_as_float(u.y << 16); s[3] += __uint_as_float(u.y & 0xFFFF0000u);
        s[4] += __uint_as_float(u.z << 16); s[5] += __uint_as_float(u.z & 0xFFFF0000u);
        s[6] += __uint_as_float(u.w << 16); s[7] += __uint_as_float(u.w & 0xFFFF0000u);
    }
    const int b = bh >> 2, h = bh & 3;
    const int grow = b * N + tile * 32 + i;
    const int col0 = (h + 1) * 128 + dg * 8;
    uint4 o;
    o.x = pack2bf(s[0], s[1]); o.y = pack2bf(s[2], s[3]);
    o.z = pack2bf(s[4], s[5]); o.w = pack2bf(s[6], s[7]);
    *reinterpret_cast<uint4*>(&cbfT[atile_idx(grow, col0, 20)]) = o;
}

// ---------------- kernel 4: fused decoder (both layers, h in LDS) ----------------
__global__ __launch_bounds__(512) void dec_kernel(
    const unsigned short* __restrict__ cbfT, const unsigned short* __restrict__ wd1t,
    const float* __restrict__ bd1, const unsigned short* __restrict__ wd2t,
    const float* __restrict__ bd2, float* __restrict__ out)
{
    const int t = threadIdx.x;
    const int lane = t & 63, lm = lane & 15, lg = lane >> 4;
    const int w = t >> 6;           // wave 0..7
    const int mm = blockIdx.x;      // 0..127
    __shared__ unsigned short hbf[8 * 512];   // h A-tiled [kk][16][32], 8 KB

    const int bbase = lm * 32 + lg * 8;
    {   // dec layer 1
        f32x4 acc0 = {0.f, 0.f, 0.f, 0.f}, acc1 = {0.f, 0.f, 0.f, 0.f};
        const int abase = mm * 20 * 512 + bbase;
        #pragma unroll 4
        for (int kk = 0; kk < 20; ++kk) {
            const bf16x8 a  = *reinterpret_cast<const bf16x8*>(cbfT + abase + kk * 512);
            const bf16x8 b0 = *reinterpret_cast<const bf16x8*>(wd1t + kk * 8192 + (2 * w) * 512 + bbase);
            const bf16x8 b1 = *reinterpret_cast<const bf16x8*>(wd1t + kk * 8192 + (2 * w + 1) * 512 + bbase);
            acc0 = __builtin_amdgcn_mfma_f32_16x16x32_bf16(a, b0, acc0, 0, 0, 0);
            acc1 = __builtin_amdgcn_mfma_f32_16x16x32_bf16(a, b1, acc1, 0, 0, 0);
        }
        const float bias0 = bd1[w * 32 + lm];
        const float bias1 = bd1[w * 32 + 16 + lm];
        unsigned short* hb = hbf + w * 512;
        #pragma unroll
        for (int r = 0; r < 4; ++r) {
            const int irow = lg * 4 + r;
            hb[irow * 32 + lm]      = tobf(fmaxf(acc0[r] + bias0, 0.f));
            hb[irow * 32 + 16 + lm] = tobf(fmaxf(acc1[r] + bias1, 0.f));
        }
    }
    __syncthreads();

    if (w < 4) {   // dec layer 2
        f32x4 acc0 = {0.f, 0.f, 0.f, 0.f}, acc1 = {0.f, 0.f, 0.f, 0.f};
        #pragma unroll
        for (int kk = 0; kk < 8; ++kk) {
            const bf16x8 a  = *reinterpret_cast<const bf16x8*>(hbf + kk * 512 + bbase);
            const bf16x8 b0 = *reinterpret_cast<const bf16x8*>(wd2t + kk * 4096 + (2 * w) * 512 + bbase);
            const bf16x8 b1 = *reinterpret_cast<const bf16x8*>(wd2t + kk * 4096 + (2 * w + 1) * 512 + bbase);
            acc0 = __builtin_amdgcn_mfma_f32_16x16x32_bf16(a, b0, acc0, 0, 0, 0);
            acc1 = __builtin_amdgcn_mfma_f32_16x16x32_bf16(a, b1, acc1, 0, 0, 0);
        }
        const float bias0 = bd2[w * 32 + lm];
        const float bias1 = bd2[w * 32 + 16 + lm];
        float* op = out + (size_t)(mm * 16) * DEC_O;
        #pragma unroll
        for (int r = 0; r < 4; ++r) {
            const int irow = lg * 4 + r;
            op[irow * DEC_O + w * 32 + lm]      = acc0[r] + bias0;
            op[irow * DEC_O + w * 32 + 16 + lm] = acc1[r] + bias1;
        }
    }
}

extern "C" void kernel_launch(void* const* d_in, const int* in_sizes, int n_in,
                              void* d_out, int out_size, void* d_ws, size_t ws_size,
                              hipStream_t stream)
{
    const float* x   = (const float*)d_in[0];
    const float* Wk  = (const float*)d_in[1];
    const float* bk  = (const float*)d_in[2];
    const float* Wq  = (const float*)d_in[3];
    const float* bq  = (const float*)d_in[4];
    const float* Wv  = (const float*)d_in[5];
    const float* bv  = (const float*)d_in[6];
    const float* Wa1 = (const float*)d_in[7];
    const float* ba1 = (const float*)d_in[8];
    const float* Wa2 = (const float*)d_in[9];
    const float* ba2 = (const float*)d_in[10];
    const float* Wd1 = (const float*)d_in[11];
    const float* bd1 = (const float*)d_in[12];
    const float* Wd2 = (const float*)d_in[13];
    const float* bd2 = (const float*)d_in[14];
    float* out = (float*)d_out;

    float* ws = (float*)d_ws;
    unsigned* hkP = (unsigned*)ws;                 // 131072 u32
    unsigned* hqP = hkP + 131072;                  // 131072 u32
    float* pkBuf = (float*)(hqP + 131072);         // 8192 f32
    float* pqBuf = pkBuf + 8192;                   // 8192 f32
    unsigned short* pBufH = (unsigned short*)(pqBuf + 8192);   // 1024*4096 u16 = 8 MB
    unsigned short* cbfT = pBufH + 4194304;        // 1310720 u16
    unsigned short* wd1t = cbfT + 1310720;         // 163840 u16
    unsigned short* wd2t = wd1t + 163840;          // 32768 u16
    unsigned short* vT8  = wd2t + 32768;           // 262144 u16
    unsigned* wa2P = (unsigned*)(vT8 + 262144);    // 16 u32

    qkvh_kernel<<<512 + 896, 384, 0, stream>>>(x, Wk, bk, Wq, bq, Wv, bv, Wa1, ba1, Wa2, ba2,
                                               Wd1, Wd2, vT8, cbfT, hkP, hqP, pkBuf, pqBuf,
                                               wd1t, wd2t, wa2P);
    attn_kernel<<<B * NH * (N / TI) * SPLIT, 256, 0, stream>>>(hkP, hqP, wa2P, pkBuf, pqBuf, vT8, pBufH);
    reduce_kernel<<<512, 256, 0, stream>>>(pBufH, cbfT);
    dec_kernel<<<128, 512, 0, stream>>>(cbfT, wd1t, bd1, wd2t, bd2, out);
}